// Round 3
// baseline (971.365 us; speedup 1.0000x reference)
//
#include <hip/hip_runtime.h>
#include <stdint.h>

#define NN 100000
#define NE 3200000
#define FIN 503
#define COUT 32
#define NSLOPE 0.2f
#define SCAN_B 98   // ceil(NN/1024)

// ---------------- Kernel A: xl = x @ W^T (+ fused a_src/a_dst) ----------------
// Row-per-lane, wave owns 8 channels. W via wave-uniform (scalar) loads,
// x staged in LDS (stride 34 -> 2-way bank alias only = free), register-
// prefetch double buffering: global loads for chunk k+1 overlap compute of k.
#define BKK 32
#define ROWS_B 64
#define XSP 34

__global__ __launch_bounds__(256, 6)
void k_gemm(const float* __restrict__ x, const float* __restrict__ W,
            const float* __restrict__ att_s, const float* __restrict__ att_d,
            float* __restrict__ xl, float* __restrict__ a_src, float* __restrict__ a_dst)
{
    __shared__ float xs[ROWS_B * XSP];   // 8.7 KB
    const int t = threadIdx.x;
    const int lane = t & 63;
    const int w = __builtin_amdgcn_readfirstlane(t >> 6);  // wave id 0..3, SGPR
    const int cw = w * 8;                                   // wave's channel base
    const int row0 = blockIdx.x * ROWS_B;
    const int row = row0 + lane;

    // staging mapping: 8 rounds of 256 lanes; round i covers rows (t>>5)+8i, k=t&31
    const int sr = t >> 5;      // 0..7
    const int sk = t & 31;      // 0..31

    float acc[8] = {0.f};
    float rv[8];

    auto load_chunk = [&](int kc) {
        #pragma unroll
        for (int i = 0; i < 8; ++i) {
            int r = sr + 8 * i;
            int rg = row0 + r;
            int kg = kc + sk;
            rv[i] = (rg < NN && kg < FIN) ? x[(size_t)rg * FIN + kg] : 0.f;
        }
    };
    auto write_lds = [&]() {
        #pragma unroll
        for (int i = 0; i < 8; ++i)
            xs[(sr + 8 * i) * XSP + sk] = rv[i];
    };

    load_chunk(0);
    write_lds();

    for (int ch = 0; ch < 16; ++ch) {
        __syncthreads();                       // LDS writes visible
        const int kc = ch * BKK;
        if (ch + 1 < 16) load_chunk((ch + 1) * BKK);   // overlap with compute

        if (kc + BKK <= FIN) {
            #pragma unroll
            for (int kq = 0; kq < 8; ++kq) {
                float2 x01 = *(const float2*)&xs[lane * XSP + kq * 4];
                float2 x23 = *(const float2*)&xs[lane * XSP + kq * 4 + 2];
                #pragma unroll
                for (int j = 0; j < 8; ++j) {
                    const float* wp = W + (size_t)(cw + j) * FIN + kc + kq * 4;
                    acc[j] += x01.x * wp[0] + x01.y * wp[1] + x23.x * wp[2] + x23.y * wp[3];
                }
            }
        } else {
            // tail chunk: xs is zero-filled past FIN, clamp W index for safety
            #pragma unroll
            for (int kq = 0; kq < 8; ++kq) {
                float2 x01 = *(const float2*)&xs[lane * XSP + kq * 4];
                float2 x23 = *(const float2*)&xs[lane * XSP + kq * 4 + 2];
                #pragma unroll
                for (int j = 0; j < 8; ++j) {
                    const float* wr = W + (size_t)(cw + j) * FIN;
                    int k0 = kc + kq * 4;
                    int i0 = (k0 + 0 > 502) ? 502 : k0 + 0;
                    int i1 = (k0 + 1 > 502) ? 502 : k0 + 1;
                    int i2 = (k0 + 2 > 502) ? 502 : k0 + 2;
                    int i3 = (k0 + 3 > 502) ? 502 : k0 + 3;
                    acc[j] += x01.x * wr[i0] + x01.y * wr[i1] + x23.x * wr[i2] + x23.y * wr[i3];
                }
            }
        }
        __syncthreads();                       // all reads done before overwrite
        if (ch + 1 < 16) write_lds();
    }

    // epilogue: xl store + cross-wave reduction of a_src/a_dst partials
    float ps = 0.f, pd = 0.f;
    #pragma unroll
    for (int j = 0; j < 8; ++j) {
        ps += acc[j] * att_s[cw + j];
        pd += acc[j] * att_d[cw + j];
    }
    if (row < NN) {
        float4 o0 = make_float4(acc[0], acc[1], acc[2], acc[3]);
        float4 o1 = make_float4(acc[4], acc[5], acc[6], acc[7]);
        *(float4*)&xl[(size_t)row * COUT + cw]     = o0;
        *(float4*)&xl[(size_t)row * COUT + cw + 4] = o1;
    }
    __syncthreads();
    xs[w * 64 + lane] = ps;
    xs[256 + w * 64 + lane] = pd;
    __syncthreads();
    if (t < 64 && row0 + t < NN) {
        float s = xs[t] + xs[64 + t] + xs[128 + t] + xs[192 + t];
        float d = xs[256 + t] + xs[320 + t] + xs[384 + t] + xs[448 + t];
        a_src[row0 + t] = s;
        a_dst[row0 + t] = d;
    }
}

// ---------------- edge-weight mean + k-const ----------------
__global__ void k_stats(const float* __restrict__ ew, const float* __restrict__ W_edge,
                        const float* __restrict__ att_e, float* __restrict__ stats)
{
    float s = 0.f;
    for (int i = blockIdx.x * blockDim.x + threadIdx.x; i < NE; i += gridDim.x * blockDim.x)
        s += ew[i];
    #pragma unroll
    for (int off = 32; off > 0; off >>= 1) s += __shfl_xor(s, off);
    if ((threadIdx.x & 63) == 0) atomicAdd(&stats[0], s);
    if (blockIdx.x == 0 && threadIdx.x == 0) {
        float k = 0.f;
        for (int c = 0; c < COUT; ++c) k += W_edge[c] * att_e[c];
        stats[1] = k;
    }
}

// ---------------- degree count ----------------
__global__ void k_count(const int* __restrict__ ei, int* __restrict__ deg)
{
    int e = blockIdx.x * 256 + threadIdx.x;
    if (e < NE) atomicAdd(&deg[ei[NE + e]], 1);
}

// ---------------- exclusive scan (3 kernels) ----------------
__global__ void k_scan1(const int* __restrict__ deg, int* __restrict__ loc, int* __restrict__ part)
{
    __shared__ int sm[256];
    int tid = threadIdx.x;
    int base = blockIdx.x * 1024 + tid * 4;
    int v[4], s = 0;
    #pragma unroll
    for (int j = 0; j < 4; ++j) {
        v[j] = (base + j < NN) ? (deg[base + j] + 1) : 0;   // +1 = self loop
        s += v[j];
    }
    sm[tid] = s;
    for (int off = 1; off < 256; off <<= 1) {
        __syncthreads();
        int tv = (tid >= off) ? sm[tid - off] : 0;
        __syncthreads();
        sm[tid] += tv;
    }
    int run = sm[tid] - s;
    #pragma unroll
    for (int j = 0; j < 4; ++j) {
        if (base + j < NN) loc[base + j] = run;
        run += v[j];
    }
    if (tid == 255) part[blockIdx.x] = sm[255];
}

__global__ void k_scan2(int* __restrict__ part)
{
    __shared__ int sm[128];
    int tid = threadIdx.x;
    int v = (tid < SCAN_B) ? part[tid] : 0;
    sm[tid] = v;
    for (int off = 1; off < 128; off <<= 1) {
        __syncthreads();
        int tv = (tid >= off) ? sm[tid - off] : 0;
        __syncthreads();
        sm[tid] += tv;
    }
    if (tid < SCAN_B) part[tid] = sm[tid] - v;
    if (tid == 127) part[SCAN_B] = sm[127];
}

__global__ void k_scan3(int* __restrict__ loc_cursor, const int* __restrict__ part, int* __restrict__ rowptr)
{
    int i = blockIdx.x * 256 + threadIdx.x;
    if (i < NN) {
        int vv = loc_cursor[i] + part[i >> 10];
        rowptr[i] = vv;
        loc_cursor[i] = vv;
    }
    if (i == 0) rowptr[NN] = part[SCAN_B];
}

// ---------------- CSR fill (edges + self loops) ----------------
__global__ void k_fill(const int* __restrict__ ei, const float* __restrict__ ew,
                       const float* __restrict__ a_src, const float* __restrict__ stats,
                       int* __restrict__ cursor, uint2* __restrict__ csr)
{
    int idx = blockIdx.x * 256 + threadIdx.x;
    float kc = stats[1];
    if (idx < NE) {
        int s = ei[idx];
        int d = ei[NE + idx];
        float pre = a_src[s] + kc * ew[idx];
        int pos = atomicAdd(&cursor[d], 1);
        csr[pos] = make_uint2((unsigned)s, __float_as_uint(pre));
    } else if (idx < NE + NN) {
        int n = idx - NE;
        float mean = stats[0] * (1.f / NE);
        float pre = a_src[n] + kc * mean;
        int pos = atomicAdd(&cursor[n], 1);
        csr[pos] = make_uint2((unsigned)n, __float_as_uint(pre));
    }
}

// ---------------- per-dst softmax aggregation (no max-sub: logits bounded) ----------------
__global__ __launch_bounds__(256)
void k_aggr(const uint2* __restrict__ csr, const int* __restrict__ rowptr,
            const float* __restrict__ a_dst, const float* __restrict__ xl,
            const float* __restrict__ bias_conv, const float* __restrict__ Wb,
            const float* __restrict__ bb, const float* __restrict__ Ww,
            const float* __restrict__ mask, float* __restrict__ out_b, float* __restrict__ hw)
{
    const int lane = threadIdx.x & 31;       // channel
    const int d = blockIdx.x * 8 + (threadIdx.x >> 5);
    if (d >= NN) return;
    const int jb = rowptr[d], je = rowptr[d + 1];
    const float adv = a_dst[d];
    float l = 0.f, acc = 0.f;
    for (int tb = jb; tb < je; tb += 32) {
        int j = tb + lane;
        float p = 0.f;
        int src = 0;
        if (j < je) {
            uint2 en = csr[j];                       // coalesced 8B per lane
            src = (int)en.x;
            float a = __uint_as_float(en.y) + adv;
            a = (a > 0.f) ? a : NSLOPE * a;
            p = __expf(a);                           // safe: |logit| < ~4
        }
        l += p;                                      // per-lane partial denom
        int cnt = min(32, je - tb);
        #pragma unroll 4
        for (int k = 0; k < cnt; ++k) {
            float pk = __shfl(p, k, 32);
            int sk = __shfl(src, k, 32);
            acc += pk * xl[(size_t)sk * COUT + lane]; // coalesced 128B gather
        }
    }
    #pragma unroll
    for (int off = 16; off > 0; off >>= 1) l += __shfl_xor(l, off, 32);
    float h = fmaxf(acc / l + bias_conv[lane], 0.f);
    float pb = h * Wb[lane];
    float pw = h * Ww[lane];
    #pragma unroll
    for (int off = 16; off > 0; off >>= 1) { pb += __shfl_xor(pb, off, 32); pw += __shfl_xor(pw, off, 32); }
    if (lane == 0) {
        out_b[d] = (pb + bb[0]) * mask[d];
        hw[d] = pw;
    }
}

// ---------------- per-edge weights head ----------------
__global__ void k_weights(const int* __restrict__ ei, const float* __restrict__ hw,
                          const float* __restrict__ bw, float* __restrict__ out_w)
{
    int e = blockIdx.x * 256 + threadIdx.x;
    if (e < NE) {
        int s = ei[e], d = ei[NE + e];
        out_w[e] = 0.5f * (hw[s] + hw[d]) + bw[0];
    }
}

extern "C" void kernel_launch(void* const* d_in, const int* in_sizes, int n_in,
                              void* d_out, int out_size, void* d_ws, size_t ws_size,
                              hipStream_t stream)
{
    const float* x        = (const float*)d_in[0];
    const int*   ei       = (const int*)d_in[1];
    const float* ew       = (const float*)d_in[2];
    const float* mask     = (const float*)d_in[3];
    const float* W_src    = (const float*)d_in[4];
    const float* att_src  = (const float*)d_in[5];
    const float* att_dst  = (const float*)d_in[6];
    const float* att_edge = (const float*)d_in[7];
    const float* W_edge   = (const float*)d_in[8];
    const float* bias_c   = (const float*)d_in[9];
    const float* Wb       = (const float*)d_in[10];
    const float* bb       = (const float*)d_in[11];
    const float* Ww       = (const float*)d_in[12];
    const float* bw       = (const float*)d_in[13];
    (void)in_sizes; (void)n_in; (void)out_size; (void)ws_size;

    char* wsp = (char*)d_ws;
    size_t off = 0;
    auto alloc = [&](size_t bytes) -> void* {
        void* p = wsp + off;
        off = (off + bytes + 255) & ~(size_t)255;
        return p;
    };
    float* xl     = (float*)alloc((size_t)NN * COUT * 4);
    float* a_src  = (float*)alloc((size_t)NN * 4);
    float* a_dst  = (float*)alloc((size_t)NN * 4);
    int*   deg    = (int*)alloc((size_t)NN * 4);
    float* stats  = (float*)alloc(256);
    int*   rowptr = (int*)alloc((size_t)(NN + 1) * 4);
    int*   cursor = (int*)alloc((size_t)NN * 4);
    int*   part   = (int*)alloc((size_t)(SCAN_B + 1) * 4);
    uint2* csr    = (uint2*)alloc((size_t)(NE + NN) * 8);
    float* hw     = (float*)alloc((size_t)NN * 4);

    float* out_w = (float*)d_out;
    float* out_b = out_w + NE;

    hipMemsetAsync(deg, 0, (size_t)NN * 4, stream);
    hipMemsetAsync(stats, 0, 8, stream);

    k_gemm   <<<(NN + ROWS_B - 1) / ROWS_B, 256, 0, stream>>>(x, W_src, att_src, att_dst, xl, a_src, a_dst);
    k_stats  <<<1024, 256, 0, stream>>>(ew, W_edge, att_edge, stats);
    k_count  <<<NE / 256, 256, 0, stream>>>(ei, deg);
    k_scan1  <<<SCAN_B, 256, 0, stream>>>(deg, cursor, part);
    k_scan2  <<<1, 128, 0, stream>>>(part);
    k_scan3  <<<(NN + 255) / 256, 256, 0, stream>>>(cursor, part, rowptr);
    k_fill   <<<(NE + NN + 255) / 256, 256, 0, stream>>>(ei, ew, a_src, stats, cursor, csr);
    k_aggr   <<<NN / 8, 256, 0, stream>>>(csr, rowptr, a_dst, xl, bias_c, Wb, bb, Ww, mask, out_b, hw);
    k_weights<<<NE / 256, 256, 0, stream>>>(ei, hw, bw, out_w);
}

// Round 4
// 850.592 us; speedup vs baseline: 1.1420x; 1.1420x over previous
//
#include <hip/hip_runtime.h>
#include <stdint.h>

#define NN 100000
#define NE 3200000
#define FIN 503
#define COUT 32
#define NSLOPE 0.2f
#define SCAN_B 98   // ceil(NN/1024)

typedef __bf16 bf16x8 __attribute__((ext_vector_type(8)));
typedef float  f32x4  __attribute__((ext_vector_type(4)));

__device__ __forceinline__ unsigned short bf1(float f) {
    unsigned u = __float_as_uint(f);
    u = (u + 0x7FFFu + ((u >> 16) & 1u)) >> 16;   // RNE truncate to bf16
    return (unsigned short)u;
}
__device__ __forceinline__ unsigned bf2(float a, float b) {
    return (unsigned)bf1(a) | ((unsigned)bf1(b) << 16);
}
__device__ __forceinline__ float unbf(unsigned short h) {
    return __uint_as_float(((unsigned)h) << 16);
}

// ---------------- Kernel A: xl(bf16) = x @ W^T via MFMA 16x16x32 bf16 ----------
// Block: 256 thr (4 waves), 64 rows x 32 ch. Wave w: rows w*16..w*16+15, both
// 16-ch tiles. W converted to bf16 LDS once per block; x staged per 32-k step.
#define GR 64
#define XSTR 40    // ushort stride per x row (32 + 8 pad) -> 80B, bank-spread
#define WSTR 520   // ushort stride per W row -> 1040B, 2-way alias only

__global__ __launch_bounds__(256)
void k_gemm(const float* __restrict__ x, const float* __restrict__ W,
            unsigned short* __restrict__ xlb)
{
    __shared__ __align__(16) unsigned short Wbf[32 * WSTR];  // 33.3 KB
    __shared__ __align__(16) unsigned short xs[GR * XSTR];   //  5.1 KB
    const int t = threadIdx.x;
    const int row0 = blockIdx.x * GR;

    // ---- convert W (32x503 fp32) -> Wbf[ch][k] bf16, zero-pad to 512 ----
    for (int idx = t; idx < 32 * 252; idx += 256) {
        int c = idx / 252, kp = (idx % 252) * 2;
        float a = W[c * FIN + kp];
        float b = (kp + 1 < FIN) ? W[c * FIN + kp + 1] : 0.f;
        *(unsigned*)&Wbf[c * WSTR + kp] = bf2(a, b);
    }
    for (int idx = t; idx < 32 * 4; idx += 256) {
        int c = idx / 4, kp = 504 + (idx % 4) * 2;
        *(unsigned*)&Wbf[c * WSTR + kp] = 0u;
    }

    const int wv   = t >> 6;       // wave 0..3
    const int lane = t & 63;
    const int m16  = lane & 15;    // row-in-tile (A) / col (B, D)
    const int quad = lane >> 4;    // 0..3
    const int sk = t & 31;         // staging k
    const int sr = t >> 5;         // staging row base 0..7

    f32x4 acc0 = {0.f, 0.f, 0.f, 0.f};
    f32x4 acc1 = {0.f, 0.f, 0.f, 0.f};

    for (int kc = 0; kc < 512; kc += 32) {
        // stage 64 rows x 32 k of x as bf16 (coalesced 128B per 32 lanes)
        #pragma unroll
        for (int i = 0; i < 8; ++i) {
            int r = sr + 8 * i;
            int grow = row0 + r;
            int kk = kc + sk;
            float v = (grow < NN && kk < FIN) ? x[(size_t)grow * FIN + kk] : 0.f;
            xs[r * XSTR + sk] = bf1(v);
        }
        __syncthreads();
        bf16x8 af  = *(const bf16x8*)&xs[(wv * 16 + m16) * XSTR + quad * 8];
        bf16x8 bf0 = *(const bf16x8*)&Wbf[m16 * WSTR + kc + quad * 8];
        bf16x8 bf1v= *(const bf16x8*)&Wbf[(16 + m16) * WSTR + kc + quad * 8];
        acc0 = __builtin_amdgcn_mfma_f32_16x16x32_bf16(af, bf0, acc0, 0, 0, 0);
        acc1 = __builtin_amdgcn_mfma_f32_16x16x32_bf16(af, bf1v, acc1, 0, 0, 0);
        __syncthreads();
    }

    // ---- epilogue: repack C-layout (row=quad*4+r, col=m16) via LDS, store bf16 ----
    float* fsm = (float*)Wbf;          // reuse; need 64*33 floats = 8.4 KB
    const int FST = 33;
    __syncthreads();
    #pragma unroll
    for (int r = 0; r < 4; ++r) {
        fsm[(wv * 16 + quad * 4 + r) * FST + m16]      = acc0[r];
        fsm[(wv * 16 + quad * 4 + r) * FST + 16 + m16] = acc1[r];
    }
    __syncthreads();
    {
        int r = t >> 2, c0 = (t & 3) * 8;
        int grow = row0 + r;
        if (grow < NN) {
            uint4 o;
            o.x = bf2(fsm[r * FST + c0 + 0], fsm[r * FST + c0 + 1]);
            o.y = bf2(fsm[r * FST + c0 + 2], fsm[r * FST + c0 + 3]);
            o.z = bf2(fsm[r * FST + c0 + 4], fsm[r * FST + c0 + 5]);
            o.w = bf2(fsm[r * FST + c0 + 6], fsm[r * FST + c0 + 7]);
            *(uint4*)&xlb[(size_t)grow * COUT + c0] = o;
        }
    }
}

// ---------------- per-node attention logits from xlb ----------------
__global__ void k_attn(const unsigned short* __restrict__ xlb,
                       const float* __restrict__ att_s, const float* __restrict__ att_d,
                       float* __restrict__ a_src, float* __restrict__ a_dst)
{
    int n = blockIdx.x * 256 + threadIdx.x;
    if (n >= NN) return;
    const unsigned short* r = xlb + (size_t)n * COUT;
    float s = 0.f, d = 0.f;
    #pragma unroll
    for (int c = 0; c < COUT; c += 2) {
        unsigned u = *(const unsigned*)&r[c];
        float v0 = __uint_as_float(u << 16);
        float v1 = __uint_as_float(u & 0xFFFF0000u);
        s += v0 * att_s[c] + v1 * att_s[c + 1];
        d += v0 * att_d[c] + v1 * att_d[c + 1];
    }
    a_src[n] = s; a_dst[n] = d;
}

// ---------------- edge-weight mean + k-const ----------------
__global__ void k_stats(const float* __restrict__ ew, const float* __restrict__ W_edge,
                        const float* __restrict__ att_e, float* __restrict__ stats)
{
    float s = 0.f;
    for (int i = blockIdx.x * blockDim.x + threadIdx.x; i < NE; i += gridDim.x * blockDim.x)
        s += ew[i];
    #pragma unroll
    for (int off = 32; off > 0; off >>= 1) s += __shfl_xor(s, off);
    if ((threadIdx.x & 63) == 0) atomicAdd(&stats[0], s);
    if (blockIdx.x == 0 && threadIdx.x == 0) {
        float k = 0.f;
        for (int c = 0; c < COUT; ++c) k += W_edge[c] * att_e[c];
        stats[1] = k;
    }
}

// ---------------- degree count + per-edge rank ----------------
__global__ void k_count(const int* __restrict__ ei, int* __restrict__ deg, int* __restrict__ rank)
{
    int e = blockIdx.x * 256 + threadIdx.x;
    if (e < NE) rank[e] = atomicAdd(&deg[ei[NE + e]], 1);
}

// ---------------- exclusive scan (3 kernels) ----------------
__global__ void k_scan1(const int* __restrict__ deg, int* __restrict__ loc, int* __restrict__ part)
{
    __shared__ int sm[256];
    int tid = threadIdx.x;
    int base = blockIdx.x * 1024 + tid * 4;
    int v[4], s = 0;
    #pragma unroll
    for (int j = 0; j < 4; ++j) {
        v[j] = (base + j < NN) ? (deg[base + j] + 1) : 0;   // +1 = self loop
        s += v[j];
    }
    sm[tid] = s;
    for (int off = 1; off < 256; off <<= 1) {
        __syncthreads();
        int tv = (tid >= off) ? sm[tid - off] : 0;
        __syncthreads();
        sm[tid] += tv;
    }
    int run = sm[tid] - s;
    #pragma unroll
    for (int j = 0; j < 4; ++j) {
        if (base + j < NN) loc[base + j] = run;
        run += v[j];
    }
    if (tid == 255) part[blockIdx.x] = sm[255];
}

__global__ void k_scan2(int* __restrict__ part)
{
    __shared__ int sm[128];
    int tid = threadIdx.x;
    int v = (tid < SCAN_B) ? part[tid] : 0;
    sm[tid] = v;
    for (int off = 1; off < 128; off <<= 1) {
        __syncthreads();
        int tv = (tid >= off) ? sm[tid - off] : 0;
        __syncthreads();
        sm[tid] += tv;
    }
    if (tid < SCAN_B) part[tid] = sm[tid] - v;
    if (tid == 127) part[SCAN_B] = sm[127];
}

__global__ void k_scan3(const int* __restrict__ loc, const int* __restrict__ part, int* __restrict__ rowptr)
{
    int i = blockIdx.x * 256 + threadIdx.x;
    if (i < NN) rowptr[i] = loc[i] + part[i >> 10];
    if (i == 0) rowptr[NN] = part[SCAN_B];
}

// ---------------- CSR fill (atomic-free: pos = rowptr + rank) ----------------
__global__ void k_fill(const int* __restrict__ ei, const float* __restrict__ ew,
                       const float* __restrict__ a_src, const float* __restrict__ stats,
                       const int* __restrict__ rowptr, const int* __restrict__ deg,
                       const int* __restrict__ rank, uint2* __restrict__ csr)
{
    int idx = blockIdx.x * 256 + threadIdx.x;
    float kc = stats[1];
    if (idx < NE) {
        int s = ei[idx];
        int d = ei[NE + idx];
        float pre = a_src[s] + kc * ew[idx];
        csr[rowptr[d] + rank[idx]] = make_uint2((unsigned)s, __float_as_uint(pre));
    } else if (idx < NE + NN) {
        int n = idx - NE;
        float mean = stats[0] * (1.f / NE);
        float pre = a_src[n] + kc * mean;
        csr[rowptr[n] + deg[n]] = make_uint2((unsigned)n, __float_as_uint(pre));
    }
}

// ---------------- per-dst softmax aggregation (bf16 gathers) ----------------
__global__ __launch_bounds__(256)
void k_aggr(const uint2* __restrict__ csr, const int* __restrict__ rowptr,
            const float* __restrict__ a_dst, const unsigned short* __restrict__ xlb,
            const float* __restrict__ bias_conv, const float* __restrict__ Wb,
            const float* __restrict__ bb, const float* __restrict__ Ww,
            const float* __restrict__ mask, float* __restrict__ out_b, float* __restrict__ hw)
{
    const int lane = threadIdx.x & 31;       // channel
    const int d = blockIdx.x * 8 + (threadIdx.x >> 5);
    if (d >= NN) return;
    const int jb = rowptr[d], je = rowptr[d + 1];
    const float adv = a_dst[d];
    float l = 0.f, acc = 0.f;
    for (int tb = jb; tb < je; tb += 32) {
        int j = tb + lane;
        float p = 0.f;
        int src = 0;
        if (j < je) {
            uint2 en = csr[j];
            src = (int)en.x;
            float a = __uint_as_float(en.y) + adv;
            a = (a > 0.f) ? a : NSLOPE * a;
            p = __expf(a);                   // safe: |logit| < ~4
        }
        l += p;
        int cnt = min(32, je - tb);
        #pragma unroll 4
        for (int k = 0; k < cnt; ++k) {
            float pk = __shfl(p, k, 32);
            int sk = __shfl(src, k, 32);
            acc += pk * unbf(xlb[(size_t)sk * COUT + lane]);  // 64B coalesced gather
        }
    }
    #pragma unroll
    for (int off = 16; off > 0; off >>= 1) l += __shfl_xor(l, off, 32);
    float h = fmaxf(acc / l + bias_conv[lane], 0.f);
    float pb = h * Wb[lane];
    float pw = h * Ww[lane];
    #pragma unroll
    for (int off = 16; off > 0; off >>= 1) { pb += __shfl_xor(pb, off, 32); pw += __shfl_xor(pw, off, 32); }
    if (lane == 0) {
        out_b[d] = (pb + bb[0]) * mask[d];
        hw[d] = pw;
    }
}

// ---------------- per-edge weights head ----------------
__global__ void k_weights(const int* __restrict__ ei, const float* __restrict__ hw,
                          const float* __restrict__ bw, float* __restrict__ out_w)
{
    int e = blockIdx.x * 256 + threadIdx.x;
    if (e < NE) {
        int s = ei[e], d = ei[NE + e];
        out_w[e] = 0.5f * (hw[s] + hw[d]) + bw[0];
    }
}

extern "C" void kernel_launch(void* const* d_in, const int* in_sizes, int n_in,
                              void* d_out, int out_size, void* d_ws, size_t ws_size,
                              hipStream_t stream)
{
    const float* x        = (const float*)d_in[0];
    const int*   ei       = (const int*)d_in[1];
    const float* ew       = (const float*)d_in[2];
    const float* mask     = (const float*)d_in[3];
    const float* W_src    = (const float*)d_in[4];
    const float* att_src  = (const float*)d_in[5];
    const float* att_dst  = (const float*)d_in[6];
    const float* att_edge = (const float*)d_in[7];
    const float* W_edge   = (const float*)d_in[8];
    const float* bias_c   = (const float*)d_in[9];
    const float* Wb       = (const float*)d_in[10];
    const float* bb       = (const float*)d_in[11];
    const float* Ww       = (const float*)d_in[12];
    const float* bw       = (const float*)d_in[13];
    (void)in_sizes; (void)n_in; (void)out_size; (void)ws_size;

    char* wsp = (char*)d_ws;
    size_t off = 0;
    auto alloc = [&](size_t bytes) -> void* {
        void* p = wsp + off;
        off = (off + bytes + 255) & ~(size_t)255;
        return p;
    };
    unsigned short* xlb = (unsigned short*)alloc((size_t)NN * COUT * 2);
    float* a_src  = (float*)alloc((size_t)NN * 4);
    float* a_dst  = (float*)alloc((size_t)NN * 4);
    int*   deg    = (int*)alloc((size_t)NN * 4);
    float* stats  = (float*)alloc(256);
    int*   loc    = (int*)alloc((size_t)NN * 4);
    int*   rowptr = (int*)alloc((size_t)(NN + 1) * 4);
    int*   part   = (int*)alloc((size_t)(SCAN_B + 1) * 4);
    int*   rank   = (int*)alloc((size_t)NE * 4);
    uint2* csr    = (uint2*)alloc((size_t)(NE + NN) * 8);
    float* hw     = (float*)alloc((size_t)NN * 4);

    float* out_w = (float*)d_out;
    float* out_b = out_w + NE;

    hipMemsetAsync(deg, 0, (size_t)NN * 4, stream);
    hipMemsetAsync(stats, 0, 8, stream);

    k_gemm   <<<(NN + GR - 1) / GR, 256, 0, stream>>>(x, W_src, xlb);
    k_attn   <<<(NN + 255) / 256, 256, 0, stream>>>(xlb, att_src, att_dst, a_src, a_dst);
    k_stats  <<<1024, 256, 0, stream>>>(ew, W_edge, att_edge, stats);
    k_count  <<<NE / 256, 256, 0, stream>>>(ei, deg, rank);
    k_scan1  <<<SCAN_B, 256, 0, stream>>>(deg, loc, part);
    k_scan2  <<<1, 128, 0, stream>>>(part);
    k_scan3  <<<(NN + 255) / 256, 256, 0, stream>>>(loc, part, rowptr);
    k_fill   <<<(NE + NN + 255) / 256, 256, 0, stream>>>(ei, ew, a_src, stats, rowptr, deg, rank, csr);
    k_aggr   <<<NN / 8, 256, 0, stream>>>(csr, rowptr, a_dst, xlb, bias_c, Wb, bb, Ww, mask, out_b, hw);
    k_weights<<<NE / 256, 256, 0, stream>>>(ei, hw, bw, out_w);
}

// Round 5
// 746.601 us; speedup vs baseline: 1.3011x; 1.1393x over previous
//
#include <hip/hip_runtime.h>
#include <stdint.h>

#define NN 100000
#define NE 3200000
#define FIN 503
#define COUT 32
#define NSLOPE 0.2f
#define SCAN_B 98   // ceil(NN/1024)

typedef __bf16 bf16x8 __attribute__((ext_vector_type(8)));
typedef float  f32x4  __attribute__((ext_vector_type(4)));

__device__ __forceinline__ unsigned short bf1(float f) {
    unsigned u = __float_as_uint(f);
    u = (u + 0x7FFFu + ((u >> 16) & 1u)) >> 16;   // RNE to bf16
    return (unsigned short)u;
}
__device__ __forceinline__ unsigned bf2(float a, float b) {
    return (unsigned)bf1(a) | ((unsigned)bf1(b) << 16);
}
__device__ __forceinline__ float unbf(unsigned short h) {
    return __uint_as_float(((unsigned)h) << 16);
}

// ---------------- W -> bf16 MFMA B-fragments, packed (one-shot) ----------------
// wfrag[chunk*128 + quad*32 + ch] = uint4 of 8 bf16: W[ch][chunk*32+quad*8 .. +7]
__global__ void k_wprep(const float* __restrict__ W, uint4* __restrict__ wfrag)
{
    int entry = blockIdx.x * 256 + threadIdx.x;
    if (entry >= 2048) return;
    int c = entry & 31;
    int quad = (entry >> 5) & 3;
    int chunk = entry >> 7;
    int kb = chunk * 32 + quad * 8;
    float v[8];
    #pragma unroll
    for (int j = 0; j < 8; ++j) {
        int k = kb + j;
        v[j] = (k < FIN) ? W[c * FIN + k] : 0.f;
    }
    uint4 o;
    o.x = bf2(v[0], v[1]); o.y = bf2(v[2], v[3]);
    o.z = bf2(v[4], v[5]); o.w = bf2(v[6], v[7]);
    wfrag[entry] = o;
}

// ---------------- Kernel A: xl(bf16) = x @ W^T via MFMA, barrier-free K-loop ----
// 256 thr = 4 waves; wave w owns rows row0+16w..+15 (m16 = row-in-tile), both
// 16-ch tiles. A-fragments loaded directly from global (8 dwords/lane; quads of
// one row cover 128 contiguous bytes -> L1-coalesced). B from L2-hot wfrag.
#define GR 64

__global__ __launch_bounds__(256)
void k_gemm(const float* __restrict__ x, const uint4* __restrict__ wfrag,
            unsigned short* __restrict__ xlb)
{
    __shared__ __align__(16) unsigned short os[GR * 40];   // 5 KB epilogue repack
    const int t = threadIdx.x;
    const int wv = t >> 6, lane = t & 63;
    const int m16 = lane & 15, quad = lane >> 4;
    const int row0 = blockIdx.x * GR;
    const int row = row0 + wv * 16 + m16;
    const int rowc = (row < NN) ? row : (NN - 1);
    const float* xr = x + (size_t)rowc * FIN;

    f32x4 acc0 = {0.f, 0.f, 0.f, 0.f};
    f32x4 acc1 = {0.f, 0.f, 0.f, 0.f};

    // chunks 0..14: no k-masking needed (k <= 14*32+31 = 479 < 503)
    #pragma unroll 5
    for (int ch = 0; ch < 15; ++ch) {
        const int kb = ch * 32 + quad * 8;
        float av[8];
        #pragma unroll
        for (int j = 0; j < 8; ++j) av[j] = xr[kb + j];
        bf16x8 af;
        #pragma unroll
        for (int j = 0; j < 8; ++j) af[j] = (__bf16)av[j];
        uint4 b0 = wfrag[ch * 128 + quad * 32 + m16];
        uint4 b1 = wfrag[ch * 128 + quad * 32 + 16 + m16];
        acc0 = __builtin_amdgcn_mfma_f32_16x16x32_bf16(af, *(bf16x8*)&b0, acc0, 0, 0, 0);
        acc1 = __builtin_amdgcn_mfma_f32_16x16x32_bf16(af, *(bf16x8*)&b1, acc1, 0, 0, 0);
    }
    // chunk 15: k = 480..511, mask k >= 503
    {
        const int kb = 480 + quad * 8;
        float av[8];
        #pragma unroll
        for (int j = 0; j < 8; ++j) av[j] = (kb + j < FIN) ? xr[kb + j] : 0.f;
        bf16x8 af;
        #pragma unroll
        for (int j = 0; j < 8; ++j) af[j] = (__bf16)av[j];
        uint4 b0 = wfrag[15 * 128 + quad * 32 + m16];
        uint4 b1 = wfrag[15 * 128 + quad * 32 + 16 + m16];
        acc0 = __builtin_amdgcn_mfma_f32_16x16x32_bf16(af, *(bf16x8*)&b0, acc0, 0, 0, 0);
        acc1 = __builtin_amdgcn_mfma_f32_16x16x32_bf16(af, *(bf16x8*)&b1, acc1, 0, 0, 0);
    }

    // epilogue: C-layout (row=quad*4+r, col=m16) -> row-major bf16 via LDS
    #pragma unroll
    for (int r = 0; r < 4; ++r) {
        int rr = wv * 16 + quad * 4 + r;
        os[rr * 40 + m16]      = bf1(acc0[r]);
        os[rr * 40 + 16 + m16] = bf1(acc1[r]);
    }
    __syncthreads();
    {
        int r = t >> 2, c0 = (t & 3) * 8;
        int grow = row0 + r;
        if (grow < NN) {
            uint4 o = *(const uint4*)&os[r * 40 + c0];
            *(uint4*)&xlb[(size_t)grow * COUT + c0] = o;
        }
    }
}

// ---------------- per-node attention logits from xlb ----------------
__global__ void k_attn(const unsigned short* __restrict__ xlb,
                       const float* __restrict__ att_s, const float* __restrict__ att_d,
                       float* __restrict__ a_src, float* __restrict__ a_dst)
{
    int n = blockIdx.x * 256 + threadIdx.x;
    if (n >= NN) return;
    const unsigned short* r = xlb + (size_t)n * COUT;
    float s = 0.f, d = 0.f;
    #pragma unroll
    for (int c = 0; c < COUT; c += 2) {
        unsigned u = *(const unsigned*)&r[c];
        float v0 = __uint_as_float(u << 16);
        float v1 = __uint_as_float(u & 0xFFFF0000u);
        s += v0 * att_s[c] + v1 * att_s[c + 1];
        d += v0 * att_d[c] + v1 * att_d[c + 1];
    }
    a_src[n] = s; a_dst[n] = d;
}

// ---------------- edge-weight mean + k-const ----------------
__global__ void k_stats(const float* __restrict__ ew, const float* __restrict__ W_edge,
                        const float* __restrict__ att_e, float* __restrict__ stats)
{
    float s = 0.f;
    for (int i = blockIdx.x * blockDim.x + threadIdx.x; i < NE; i += gridDim.x * blockDim.x)
        s += ew[i];
    #pragma unroll
    for (int off = 32; off > 0; off >>= 1) s += __shfl_xor(s, off);
    if ((threadIdx.x & 63) == 0) atomicAdd(&stats[0], s);
    if (blockIdx.x == 0 && threadIdx.x == 0) {
        float k = 0.f;
        for (int c = 0; c < COUT; ++c) k += W_edge[c] * att_e[c];
        stats[1] = k;
    }
}

// ---------------- degree count + per-edge rank ----------------
__global__ void k_count(const int* __restrict__ ei, int* __restrict__ deg, int* __restrict__ rank)
{
    int e = blockIdx.x * 256 + threadIdx.x;
    if (e < NE) rank[e] = atomicAdd(&deg[ei[NE + e]], 1);
}

// ---------------- exclusive scan (3 kernels) ----------------
__global__ void k_scan1(const int* __restrict__ deg, int* __restrict__ loc, int* __restrict__ part)
{
    __shared__ int sm[256];
    int tid = threadIdx.x;
    int base = blockIdx.x * 1024 + tid * 4;
    int v[4], s = 0;
    #pragma unroll
    for (int j = 0; j < 4; ++j) {
        v[j] = (base + j < NN) ? (deg[base + j] + 1) : 0;   // +1 = self loop
        s += v[j];
    }
    sm[tid] = s;
    for (int off = 1; off < 256; off <<= 1) {
        __syncthreads();
        int tv = (tid >= off) ? sm[tid - off] : 0;
        __syncthreads();
        sm[tid] += tv;
    }
    int run = sm[tid] - s;
    #pragma unroll
    for (int j = 0; j < 4; ++j) {
        if (base + j < NN) loc[base + j] = run;
        run += v[j];
    }
    if (tid == 255) part[blockIdx.x] = sm[255];
}

__global__ void k_scan2(int* __restrict__ part)
{
    __shared__ int sm[128];
    int tid = threadIdx.x;
    int v = (tid < SCAN_B) ? part[tid] : 0;
    sm[tid] = v;
    for (int off = 1; off < 128; off <<= 1) {
        __syncthreads();
        int tv = (tid >= off) ? sm[tid - off] : 0;
        __syncthreads();
        sm[tid] += tv;
    }
    if (tid < SCAN_B) part[tid] = sm[tid] - v;
    if (tid == 127) part[SCAN_B] = sm[127];
}

__global__ void k_scan3(const int* __restrict__ loc, const int* __restrict__ part, int* __restrict__ rowptr)
{
    int i = blockIdx.x * 256 + threadIdx.x;
    if (i < NN) rowptr[i] = loc[i] + part[i >> 10];
    if (i == 0) rowptr[NN] = part[SCAN_B];
}

// ---------------- CSR fill (atomic-free: pos = rowptr + rank) ----------------
__global__ void k_fill(const int* __restrict__ ei, const float* __restrict__ ew,
                       const float* __restrict__ a_src, const float* __restrict__ stats,
                       const int* __restrict__ rowptr, const int* __restrict__ deg,
                       const int* __restrict__ rank, uint2* __restrict__ csr)
{
    int idx = blockIdx.x * 256 + threadIdx.x;
    float kc = stats[1];
    if (idx < NE) {
        int s = ei[idx];
        int d = ei[NE + idx];
        float pre = a_src[s] + kc * ew[idx];
        csr[rowptr[d] + rank[idx]] = make_uint2((unsigned)s, __float_as_uint(pre));
    } else if (idx < NE + NN) {
        int n = idx - NE;
        float mean = stats[0] * (1.f / NE);
        float pre = a_src[n] + kc * mean;
        csr[rowptr[n] + deg[n]] = make_uint2((unsigned)n, __float_as_uint(pre));
    }
}

// ---------------- per-dst softmax aggregation (bf16 gathers) ----------------
__global__ __launch_bounds__(256)
void k_aggr(const uint2* __restrict__ csr, const int* __restrict__ rowptr,
            const float* __restrict__ a_dst, const unsigned short* __restrict__ xlb,
            const float* __restrict__ bias_conv, const float* __restrict__ Wb,
            const float* __restrict__ bb, const float* __restrict__ Ww,
            const float* __restrict__ mask, float* __restrict__ out_b, float* __restrict__ hw)
{
    const int lane = threadIdx.x & 31;       // channel
    const int d = blockIdx.x * 8 + (threadIdx.x >> 5);
    if (d >= NN) return;
    const int jb = rowptr[d], je = rowptr[d + 1];
    const float adv = a_dst[d];
    float l = 0.f, acc = 0.f;
    for (int tb = jb; tb < je; tb += 32) {
        int j = tb + lane;
        float p = 0.f;
        int src = 0;
        if (j < je) {
            uint2 en = csr[j];
            src = (int)en.x;
            float a = __uint_as_float(en.y) + adv;
            a = (a > 0.f) ? a : NSLOPE * a;
            p = __expf(a);                   // safe: |logit| < ~4
        }
        l += p;
        int cnt = min(32, je - tb);
        #pragma unroll 4
        for (int k = 0; k < cnt; ++k) {
            float pk = __shfl(p, k, 32);
            int sk = __shfl(src, k, 32);
            acc += pk * unbf(xlb[(size_t)sk * COUT + lane]);  // 64B coalesced gather
        }
    }
    #pragma unroll
    for (int off = 16; off > 0; off >>= 1) l += __shfl_xor(l, off, 32);
    float h = fmaxf(acc / l + bias_conv[lane], 0.f);
    float pb = h * Wb[lane];
    float pw = h * Ww[lane];
    #pragma unroll
    for (int off = 16; off > 0; off >>= 1) { pb += __shfl_xor(pb, off, 32); pw += __shfl_xor(pw, off, 32); }
    if (lane == 0) {
        out_b[d] = (pb + bb[0]) * mask[d];
        hw[d] = pw;
    }
}

// ---------------- per-edge weights head ----------------
__global__ void k_weights(const int* __restrict__ ei, const float* __restrict__ hw,
                          const float* __restrict__ bw, float* __restrict__ out_w)
{
    int e = blockIdx.x * 256 + threadIdx.x;
    if (e < NE) {
        int s = ei[e], d = ei[NE + e];
        out_w[e] = 0.5f * (hw[s] + hw[d]) + bw[0];
    }
}

extern "C" void kernel_launch(void* const* d_in, const int* in_sizes, int n_in,
                              void* d_out, int out_size, void* d_ws, size_t ws_size,
                              hipStream_t stream)
{
    const float* x        = (const float*)d_in[0];
    const int*   ei       = (const int*)d_in[1];
    const float* ew       = (const float*)d_in[2];
    const float* mask     = (const float*)d_in[3];
    const float* W_src    = (const float*)d_in[4];
    const float* att_src  = (const float*)d_in[5];
    const float* att_dst  = (const float*)d_in[6];
    const float* att_edge = (const float*)d_in[7];
    const float* W_edge   = (const float*)d_in[8];
    const float* bias_c   = (const float*)d_in[9];
    const float* Wb       = (const float*)d_in[10];
    const float* bb       = (const float*)d_in[11];
    const float* Ww       = (const float*)d_in[12];
    const float* bw       = (const float*)d_in[13];
    (void)in_sizes; (void)n_in; (void)out_size; (void)ws_size;

    char* wsp = (char*)d_ws;
    size_t off = 0;
    auto alloc = [&](size_t bytes) -> void* {
        void* p = wsp + off;
        off = (off + bytes + 255) & ~(size_t)255;
        return p;
    };
    unsigned short* xlb = (unsigned short*)alloc((size_t)NN * COUT * 2);
    uint4* wfrag  = (uint4*)alloc(2048 * 16);
    float* a_src  = (float*)alloc((size_t)NN * 4);
    float* a_dst  = (float*)alloc((size_t)NN * 4);
    int*   deg    = (int*)alloc((size_t)NN * 4);
    float* stats  = (float*)alloc(256);
    int*   loc    = (int*)alloc((size_t)NN * 4);
    int*   rowptr = (int*)alloc((size_t)(NN + 1) * 4);
    int*   part   = (int*)alloc((size_t)(SCAN_B + 1) * 4);
    int*   rank   = (int*)alloc((size_t)NE * 4);
    uint2* csr    = (uint2*)alloc((size_t)(NE + NN) * 8);
    float* hw     = (float*)alloc((size_t)NN * 4);

    float* out_w = (float*)d_out;
    float* out_b = out_w + NE;

    hipMemsetAsync(deg, 0, (size_t)NN * 4, stream);
    hipMemsetAsync(stats, 0, 8, stream);

    k_wprep  <<<8, 256, 0, stream>>>(W_src, wfrag);
    k_gemm   <<<(NN + GR - 1) / GR, 256, 0, stream>>>(x, wfrag, xlb);
    k_attn   <<<(NN + 255) / 256, 256, 0, stream>>>(xlb, att_src, att_dst, a_src, a_dst);
    k_stats  <<<1024, 256, 0, stream>>>(ew, W_edge, att_edge, stats);
    k_count  <<<NE / 256, 256, 0, stream>>>(ei, deg, rank);
    k_scan1  <<<SCAN_B, 256, 0, stream>>>(deg, loc, part);
    k_scan2  <<<1, 128, 0, stream>>>(part);
    k_scan3  <<<(NN + 255) / 256, 256, 0, stream>>>(loc, part, rowptr);
    k_fill   <<<(NE + NN + 255) / 256, 256, 0, stream>>>(ei, ew, a_src, stats, rowptr, deg, rank, csr);
    k_aggr   <<<NN / 8, 256, 0, stream>>>(csr, rowptr, a_dst, xlb, bias_c, Wb, bb, Ww, mask, out_b, hw);
    k_weights<<<NE / 256, 256, 0, stream>>>(ei, hw, bw, out_w);
}